// Round 3
// baseline (6752.612 us; speedup 1.0000x reference)
//
#include <hip/hip_runtime.h>
#include <cstdint>
#include <cstddef>

// ---------------- types ----------------
typedef _Float16 half8 __attribute__((ext_vector_type(8)));
typedef float floatx4 __attribute__((ext_vector_type(4)));

typedef __attribute__((address_space(3))) unsigned lds_u32;
typedef const __attribute__((address_space(1))) unsigned glb_u32;

#define BK 32

__device__ __forceinline__ void glds16(const void* g, void* l) {
    // async global->LDS, 16B per lane; LDS dest = wave-uniform base + lane*16
    __builtin_amdgcn_global_load_lds((glb_u32*)g, (lds_u32*)l, 16, 0, 0);
}

__device__ __forceinline__ float fast_tanh(float x) {
    float ax = fabsf(x);
    float e  = __expf(-2.0f * ax);
    float t  = (1.0f - e) / (1.0f + e);
    return x < 0.0f ? -t : t;
}

// ---------------- GEMM core, double-buffered, fragment-contiguous LDS -------
// C[TBM x TBN] = A[TBM x K] * BT[TBN x K]^T, both fp16 row-major (BT = B^T).
// LDS layout: per 16-row chunk c, unit (16B) index = c*64 + quad*16 + l16
// holds A[c*16 + l16][k0 + quad*8 .. +8). Staging lane (q=lane>>4, l=lane&15)
// fetches that element range; fragment read is then base + lane*16 — the
// canonical conflict-free LDS pattern (round-2 layout was 8-way conflicted:
// 64B row stride => dword-group (4*l16+quad)%8 aliases 8 lanes/group).
template <int TBM, int TBN, int MF, int NF>
__device__ __forceinline__ void gemm_acc_db(const _Float16* __restrict__ A,
                                            const _Float16* __restrict__ BT,
                                            int K, floatx4 acc[MF][NF]) {
    constexpr int CW = TBN / (16 * NF);   // waves along n
    static_assert((TBM / (16 * MF)) * CW == 4, "wave layout must use 4 waves");

    __shared__ __align__(16) _Float16 As[2][TBM * BK];
    __shared__ __align__(16) _Float16 Bs[2][TBN * BK];

    const int tid  = threadIdx.x;
    const int lane = tid & 63;
    const int wid  = tid >> 6;
    const size_t m0 = (size_t)blockIdx.x * TBM;
    const size_t n0 = (size_t)blockIdx.y * TBN;

    const int srow = lane & 15;          // staging: row within 16-row chunk
    const int skc  = (lane >> 4) * 8;    // staging: k-offset (fp16 elements)
    const int wm   = (wid / CW) * (16 * MF);
    const int wn   = (wid % CW) * (16 * NF);

#pragma unroll
    for (int i = 0; i < MF; ++i)
#pragma unroll
        for (int j = 0; j < NF; ++j)
            acc[i][j] = 0.0f;

    auto stage = [&](int buf, int k0) {
        // one glds16 issue = 16 rows x 32 k (1 KB); chunk c at As + c*512 elems
#pragma unroll
        for (int c = wid; c < TBM / 16; c += 4)
            glds16(A + (m0 + c * 16 + srow) * (size_t)K + k0 + skc,
                   &As[buf][c * 512]);
#pragma unroll
        for (int c = wid; c < TBN / 16; c += 4)
            glds16(BT + (n0 + c * 16 + srow) * (size_t)K + k0 + skc,
                   &Bs[buf][c * 512]);
    };

    stage(0, 0);
    int cur = 0;
    for (int k0 = 0; k0 < K; k0 += BK) {
        __syncthreads();                           // buf[cur] ready (vmcnt drain)
        if (k0 + BK < K) stage(cur ^ 1, k0 + BK);  // overlap with MFMAs below

        half8 av[MF], bv[NF];
#pragma unroll
        for (int i = 0; i < MF; ++i)               // lane-contiguous: zero conflicts
            av[i] = *(const half8*)(&As[cur][((wm >> 4) + i) * 512 + lane * 8]);
#pragma unroll
        for (int j = 0; j < NF; ++j)
            bv[j] = *(const half8*)(&Bs[cur][((wn >> 4) + j) * 512 + lane * 8]);
#pragma unroll
        for (int i = 0; i < MF; ++i)
#pragma unroll
            for (int j = 0; j < NF; ++j)
                acc[i][j] = __builtin_amdgcn_mfma_f32_16x16x32_f16(av[i], bv[j], acc[i][j], 0, 0, 0);
        cur ^= 1;
    }
}

// C/D layout (verified m89/m91): col = lane&15, row = quad*4 + reg.

// ---------------- GEMM + bias (+ t*brow) + tanh -> fp16 out ----------------
template <bool WITH_T>
__global__ __launch_bounds__(256)
void gemm_bias_tanh(const _Float16* __restrict__ A, const _Float16* __restrict__ BT,
                    _Float16* __restrict__ out, const float* __restrict__ bias,
                    const float* __restrict__ brow, float t, int N, int K) {
    floatx4 acc[4][4];
    gemm_acc_db<128, 128, 4, 4>(A, BT, K, acc);

    const int tid  = threadIdx.x;
    const int lane = tid & 63;
    const int wid  = tid >> 6;
    const int quad = lane >> 4;
    const int l16  = lane & 15;
    const size_t m0 = (size_t)blockIdx.x * 128 + (size_t)(wid / 2) * 64;
    const size_t n0 = (size_t)blockIdx.y * 128 + (size_t)(wid % 2) * 64;

#pragma unroll
    for (int j = 0; j < 4; ++j) {
        const size_t col = n0 + j * 16 + l16;
        float b = bias[col];
        if (WITH_T) b += t * brow[col];
#pragma unroll
        for (int i = 0; i < 4; ++i) {
            const size_t rbase = m0 + i * 16 + quad * 4;
#pragma unroll
            for (int r = 0; r < 4; ++r) {
                out[(rbase + r) * (size_t)N + col] = (_Float16)fast_tanh(acc[i][j][r] + b);
            }
        }
    }
}

// ---------------- GEMM3 (64x128 tile) + fused RK4 stage update ----------------
// stage 0: accb = k;            x = fp16(h + c*k)
// stage 1: accb += 2k;          x = fp16(h + c*k)      (c = dt/2)
// stage 2: accb += 2k;          x = fp16(h + c*k)      (c = dt)
// stage 3: h += dt/6*(accb+k);  x = fp16(h)
__global__ __launch_bounds__(256)
void gemm_k_stage(const _Float16* __restrict__ A, const _Float16* __restrict__ BT,
                  const float* __restrict__ bias, float* __restrict__ hstate,
                  float* __restrict__ accb, _Float16* __restrict__ x,
                  int stage, float c, float dt6, int N, int K) {
    floatx4 acc[4][2];
    gemm_acc_db<64, 128, 4, 2>(A, BT, K, acc);

    const int tid  = threadIdx.x;
    const int lane = tid & 63;
    const int wid  = tid >> 6;
    const int quad = lane >> 4;
    const int l16  = lane & 15;
    // wave layout for <64,128,4,2>: CW=4 -> wm = 0, wn = wid*32
    const size_t m0 = (size_t)blockIdx.x * 64;
    const size_t n0 = (size_t)blockIdx.y * 128 + (size_t)wid * 32;

#pragma unroll
    for (int j = 0; j < 2; ++j) {
        const size_t col = n0 + j * 16 + l16;
        const float b = bias[col];
#pragma unroll
        for (int i = 0; i < 4; ++i) {
            const size_t rbase = m0 + i * 16 + quad * 4;
#pragma unroll
            for (int r = 0; r < 4; ++r) {
                const size_t idx = (rbase + r) * (size_t)N + col;
                const float k = acc[i][j][r] + b;
                if (stage == 0) {
                    accb[idx] = k;
                    x[idx] = (_Float16)(hstate[idx] + c * k);
                } else if (stage < 3) {
                    accb[idx] += 2.0f * k;
                    x[idx] = (_Float16)(hstate[idx] + c * k);
                } else {
                    const float hn = hstate[idx] + dt6 * (accb[idx] + k);
                    hstate[idx] = hn;
                    x[idx] = (_Float16)hn;
                }
            }
        }
    }
}

// ---------------- setup kernels ----------------
// LDS-tiled transpose: WT[n*K + k] = (fp16) W[k*N + n]; W is K x N fp32.
// 32x32 tile, block (32,8); both read and write coalesced.
__global__ __launch_bounds__(256)
void transposeW(const float* __restrict__ W, _Float16* __restrict__ WT,
                int K, int N) {
    __shared__ float tile[32][33];
    const int tx = threadIdx.x;          // 0..31
    const int ty = threadIdx.y;          // 0..7
    const int n0 = blockIdx.x * 32;
    const int k0 = blockIdx.y * 32;
#pragma unroll
    for (int r = ty; r < 32; r += 8)
        tile[r][tx] = W[(size_t)(k0 + r) * N + n0 + tx];
    __syncthreads();
#pragma unroll
    for (int r = ty; r < 32; r += 8)
        WT[(size_t)(n0 + r) * K + k0 + tx] = (_Float16)tile[tx][r];
}

__global__ void copy_row(const float* __restrict__ W1, float* __restrict__ w1row, int N) {
    const int n = blockIdx.x * 256 + threadIdx.x;
    if (n < N) w1row[n] = W1[(size_t)1024 * N + n];
}

__global__ void init_h(const float* __restrict__ h0, float* __restrict__ hstate,
                       _Float16* __restrict__ x, int n) {
    const int i = blockIdx.x * 256 + threadIdx.x;
    if (i < n) {
        const float v = h0[i];
        hstate[i] = v;
        x[i] = (_Float16)v;
    }
}

// ---------------- launch ----------------
extern "C" void kernel_launch(void* const* d_in, const int* in_sizes, int n_in,
                              void* d_out, int out_size, void* d_ws, size_t ws_size,
                              hipStream_t stream) {
    const int B = 4096, H = 1024, H2 = 2048;

    const float* h0 = (const float*)d_in[0];
    const float* W1 = (const float*)d_in[1];  // (1025, 2048)
    const float* b1 = (const float*)d_in[2];  // (2048,)
    const float* W2 = (const float*)d_in[3];  // (2048, 2048)
    const float* b2 = (const float*)d_in[4];  // (2048,)
    const float* W3 = (const float*)d_in[5];  // (2048, 1024)
    const float* b3 = (const float*)d_in[6];  // (1024,)

    float* hstate = (float*)d_out;            // B*H fp32 state, final answer

    char* ws = (char*)d_ws;
    _Float16* x    = (_Float16*)ws; ws += (size_t)B * H  * 2;  // GEMM1 input
    _Float16* a1   = (_Float16*)ws; ws += (size_t)B * H2 * 2;  // layer-1 act
    _Float16* a2   = (_Float16*)ws; ws += (size_t)B * H2 * 2;  // layer-2 act
    float*    accb = (float*)ws;    ws += (size_t)B * H  * 4;  // RK4 k-accum
    _Float16* W1T  = (_Float16*)ws; ws += (size_t)H2 * H  * 2; // (2048,1024)
    _Float16* W2T  = (_Float16*)ws; ws += (size_t)H2 * H2 * 2; // (2048,2048)
    _Float16* W3T  = (_Float16*)ws; ws += (size_t)H  * H2 * 2; // (1024,2048)
    float*   w1row = (float*)ws;    ws += (size_t)H2 * 4;      // t-row of W1, fp32

    // weight conversion + transpose (runs every call; weights restored by harness)
    const dim3 tblk(32, 8);
    transposeW<<<dim3(H2 / 32, H  / 32), tblk, 0, stream>>>(W1, W1T, H,  H2);
    transposeW<<<dim3(H2 / 32, H2 / 32), tblk, 0, stream>>>(W2, W2T, H2, H2);
    transposeW<<<dim3(H  / 32, H2 / 32), tblk, 0, stream>>>(W3, W3T, H2, H);
    copy_row<<<dim3(H2 / 256), 256, 0, stream>>>(W1, w1row, H2);
    init_h<<<dim3((B * H + 255) / 256), 256, 0, stream>>>(h0, hstate, x, B * H);

    const float dt  = 0.1f;
    const float dt2 = 0.05f;
    const float dt6 = dt / 6.0f;

    const dim3 blk(256);
    const dim3 g1grid(B / 128, H2 / 128);   // (32,16) = 512 blocks
    const dim3 g2grid(B / 128, H2 / 128);   // (32,16) = 512 blocks
    const dim3 g3grid(B / 64,  H  / 128);   // (64,8)  = 512 blocks

    for (int s = 0; s < 10; ++s) {
        const float ti = (float)s * dt;

        // k1 = f(ti, h)
        gemm_bias_tanh<true ><<<g1grid, blk, 0, stream>>>(x,  W1T, a1, b1, w1row, ti,        H2, H);
        gemm_bias_tanh<false><<<g2grid, blk, 0, stream>>>(a1, W2T, a2, b2, nullptr, 0.f,     H2, H2);
        gemm_k_stage<<<g3grid, blk, 0, stream>>>(a2, W3T, b3, hstate, accb, x, 0, dt2, dt6,  H,  H2);

        // k2 = f(ti+dt/2, h + dt/2*k1)
        gemm_bias_tanh<true ><<<g1grid, blk, 0, stream>>>(x,  W1T, a1, b1, w1row, ti + dt2,  H2, H);
        gemm_bias_tanh<false><<<g2grid, blk, 0, stream>>>(a1, W2T, a2, b2, nullptr, 0.f,     H2, H2);
        gemm_k_stage<<<g3grid, blk, 0, stream>>>(a2, W3T, b3, hstate, accb, x, 1, dt2, dt6,  H,  H2);

        // k3 = f(ti+dt/2, h + dt/2*k2)
        gemm_bias_tanh<true ><<<g1grid, blk, 0, stream>>>(x,  W1T, a1, b1, w1row, ti + dt2,  H2, H);
        gemm_bias_tanh<false><<<g2grid, blk, 0, stream>>>(a1, W2T, a2, b2, nullptr, 0.f,     H2, H2);
        gemm_k_stage<<<g3grid, blk, 0, stream>>>(a2, W3T, b3, hstate, accb, x, 2, dt,  dt6,  H,  H2);

        // k4 = f(ti+dt, h + dt*k3); h += dt/6*(k1+2k2+2k3+k4)
        gemm_bias_tanh<true ><<<g1grid, blk, 0, stream>>>(x,  W1T, a1, b1, w1row, ti + dt,   H2, H);
        gemm_bias_tanh<false><<<g2grid, blk, 0, stream>>>(a1, W2T, a2, b2, nullptr, 0.f,     H2, H2);
        gemm_k_stage<<<g3grid, blk, 0, stream>>>(a2, W3T, b3, hstate, accb, x, 3, dt,  dt6,  H,  H2);
    }
}

// Round 4
// 5253.561 us; speedup vs baseline: 1.2853x; 1.2853x over previous
//
#include <hip/hip_runtime.h>
#include <cstdint>
#include <cstddef>

// ---------------- types ----------------
typedef _Float16 half8 __attribute__((ext_vector_type(8)));
typedef float floatx4 __attribute__((ext_vector_type(4)));

typedef __attribute__((address_space(3))) unsigned lds_u32;
typedef const __attribute__((address_space(1))) unsigned glb_u32;

#define BK 32

__device__ __forceinline__ void glds16(const void* g, void* l) {
    // async global->LDS, 16B per lane; LDS dest = wave-uniform base + lane*16
    __builtin_amdgcn_global_load_lds((glb_u32*)g, (lds_u32*)l, 16, 0, 0);
}

__device__ __forceinline__ float fast_tanh(float x) {
    float ax = fabsf(x);
    float e  = __expf(-2.0f * ax);
    float t  = (1.0f - e) / (1.0f + e);
    return x < 0.0f ? -t : t;
}

// ---------------- XCD-aware block mapping ----------------
// Assumes (heuristic, perf-only) consecutive blockIdx round-robin across the
// 8 XCDs: xcd = id % 8. Each XCD gets NPX n-tiles (B-slice stays L2-resident)
// and MT/XPG m-tiles; adjacent slots alternate n so A panels are L2-hot.
// Requires: NG = NT/NPX <= 8, 8 % NG == 0, all pow2 here.
template <int MT, int NT, int NPX>
__device__ __forceinline__ void map_block(int id, int& mt, int& nt) {
    constexpr int NG  = NT / NPX;   // n-groups
    constexpr int XPG = 8 / NG;     // XCDs per group
    const int xcd  = id & 7;
    const int slot = id >> 3;
    nt = (xcd % NG) * NPX + (slot % NPX);
    mt = (xcd / NG) * (MT / XPG) + slot / NPX;
}

// ---------------- GEMM core, double-buffered, XOR-swizzled LDS -------------
// C[TBM x TBN] = A[TBM x K] * BT[TBN x K]^T, both fp16 row-major (BT = B^T).
// Staging (coalesced, like round-1): lane j covers row j>>2, 16B k-chunk
//   kq = (j&3) ^ ((j>>2)&3)  within the row's 64B — same 64B span per 4 lanes.
// LDS: chunk c (16 rows x 32 k) at elems [c*512, c*512+512); unit(row,kq) =
//   row*4 + (kq ^ (row&3)). Fragment read unit = l16*4 + (quad^(l16&3)):
//   each 8-lane window -> 4 bank-groups 2-way = free (m136).
template <int TBM, int TBN, int MF, int NF>
__device__ __forceinline__ void gemm_acc_db(const _Float16* __restrict__ A,
                                            const _Float16* __restrict__ BT,
                                            size_t m0, size_t n0,
                                            int K, floatx4 acc[MF][NF]) {
    constexpr int CW = TBN / (16 * NF);   // waves along n
    static_assert((TBM / (16 * MF)) * CW == 4, "wave layout must use 4 waves");

    __shared__ __align__(16) _Float16 As[2][TBM * BK];
    __shared__ __align__(16) _Float16 Bs[2][TBN * BK];

    const int tid  = threadIdx.x;
    const int lane = tid & 63;
    const int wid  = tid >> 6;

    const int srow = lane >> 2;                  // row within 16-row chunk
    const int skq  = (lane & 3) ^ (srow & 3);    // swizzled 8-elem k-chunk
    const int quad = lane >> 4;
    const int l16  = lane & 15;
    const int wm   = (wid / CW) * (16 * MF);
    const int wn   = (wid % CW) * (16 * NF);

#pragma unroll
    for (int i = 0; i < MF; ++i)
#pragma unroll
        for (int j = 0; j < NF; ++j)
            acc[i][j] = 0.0f;

    auto stage = [&](int buf, int k0) {
        // one glds16 issue = 16 rows x 32 k (1 KB), coalesced 64B per 4 lanes
#pragma unroll
        for (int c = wid; c < TBM / 16; c += 4)
            glds16(A + (m0 + c * 16 + srow) * (size_t)K + k0 + skq * 8,
                   &As[buf][c * 512]);
#pragma unroll
        for (int c = wid; c < TBN / 16; c += 4)
            glds16(BT + (n0 + c * 16 + srow) * (size_t)K + k0 + skq * 8,
                   &Bs[buf][c * 512]);
    };

    const int rdoff = l16 * 32 + ((quad ^ (l16 & 3)) << 3);  // swizzled frag addr

    stage(0, 0);
    int cur = 0;
    for (int k0 = 0; k0 < K; k0 += BK) {
        __syncthreads();                           // buf[cur] ready (vmcnt drain)
        if (k0 + BK < K) stage(cur ^ 1, k0 + BK);  // overlap with MFMAs below

        half8 av[MF], bv[NF];
#pragma unroll
        for (int i = 0; i < MF; ++i)
            av[i] = *(const half8*)(&As[cur][((wm >> 4) + i) * 512 + rdoff]);
#pragma unroll
        for (int j = 0; j < NF; ++j)
            bv[j] = *(const half8*)(&Bs[cur][((wn >> 4) + j) * 512 + rdoff]);
#pragma unroll
        for (int i = 0; i < MF; ++i)
#pragma unroll
            for (int j = 0; j < NF; ++j)
                acc[i][j] = __builtin_amdgcn_mfma_f32_16x16x32_f16(av[i], bv[j], acc[i][j], 0, 0, 0);
        cur ^= 1;
    }
}

// C/D layout (verified m89/m91): col = lane&15, row = quad*4 + reg.

// ---------------- GEMM + bias (+ t*brow) + tanh -> fp16 out ----------------
// 128x128 tile, 1-D grid of (M/128)*(N/128) blocks, XCD-mapped.
template <bool WITH_T, int MT, int NT>
__global__ __launch_bounds__(256)
void gemm_bias_tanh(const _Float16* __restrict__ A, const _Float16* __restrict__ BT,
                    _Float16* __restrict__ out, const float* __restrict__ bias,
                    const float* __restrict__ brow, float t, int N, int K) {
    int mt, nt;
    map_block<MT, NT, 4>(blockIdx.x, mt, nt);
    const size_t bm0 = (size_t)mt * 128;
    const size_t bn0 = (size_t)nt * 128;

    floatx4 acc[4][4];
    gemm_acc_db<128, 128, 4, 4>(A, BT, bm0, bn0, K, acc);

    const int tid  = threadIdx.x;
    const int lane = tid & 63;
    const int wid  = tid >> 6;
    const int quad = lane >> 4;
    const int l16  = lane & 15;
    const size_t m0 = bm0 + (size_t)(wid / 2) * 64;
    const size_t n0 = bn0 + (size_t)(wid % 2) * 64;

#pragma unroll
    for (int j = 0; j < 4; ++j) {
        const size_t col = n0 + j * 16 + l16;
        float b = bias[col];
        if (WITH_T) b += t * brow[col];
#pragma unroll
        for (int i = 0; i < 4; ++i) {
            const size_t rbase = m0 + i * 16 + quad * 4;
#pragma unroll
            for (int r = 0; r < 4; ++r) {
                out[(rbase + r) * (size_t)N + col] = (_Float16)fast_tanh(acc[i][j][r] + b);
            }
        }
    }
}

// ---------------- GEMM3 (64x128 tile) + fused RK4 stage update ----------------
// stage 0: accb = k;            x = fp16(h + c*k)
// stage 1: accb += 2k;          x = fp16(h + c*k)      (c = dt/2)
// stage 2: accb += 2k;          x = fp16(h + c*k)      (c = dt)
// stage 3: h += dt/6*(accb+k);  x = fp16(h)
__global__ __launch_bounds__(256)
void gemm_k_stage(const _Float16* __restrict__ A, const _Float16* __restrict__ BT,
                  const float* __restrict__ bias, float* __restrict__ hstate,
                  float* __restrict__ accb, _Float16* __restrict__ x,
                  int stage, float c, float dt6, int N, int K) {
    int mt, nt;
    map_block<64, 8, 2>(blockIdx.x, mt, nt);
    const size_t bm0 = (size_t)mt * 64;
    const size_t bn0 = (size_t)nt * 128;

    floatx4 acc[4][2];
    gemm_acc_db<64, 128, 4, 2>(A, BT, bm0, bn0, K, acc);

    const int tid  = threadIdx.x;
    const int lane = tid & 63;
    const int wid  = tid >> 6;
    const int quad = lane >> 4;
    const int l16  = lane & 15;
    // wave layout for <64,128,4,2>: CW=4 -> wm = 0, wn = wid*32
    const size_t m0 = bm0;
    const size_t n0 = bn0 + (size_t)wid * 32;

#pragma unroll
    for (int j = 0; j < 2; ++j) {
        const size_t col = n0 + j * 16 + l16;
        const float b = bias[col];
#pragma unroll
        for (int i = 0; i < 4; ++i) {
            const size_t rbase = m0 + i * 16 + quad * 4;
#pragma unroll
            for (int r = 0; r < 4; ++r) {
                const size_t idx = (rbase + r) * (size_t)N + col;
                const float k = acc[i][j][r] + b;
                if (stage == 0) {
                    accb[idx] = k;
                    x[idx] = (_Float16)(hstate[idx] + c * k);
                } else if (stage < 3) {
                    accb[idx] += 2.0f * k;
                    x[idx] = (_Float16)(hstate[idx] + c * k);
                } else {
                    const float hn = hstate[idx] + dt6 * (accb[idx] + k);
                    hstate[idx] = hn;
                    x[idx] = (_Float16)hn;
                }
            }
        }
    }
}

// ---------------- setup kernels ----------------
// LDS-tiled transpose: WT[n*K + k] = (fp16) W[k*N + n]; W is K x N fp32.
__global__ __launch_bounds__(256)
void transposeW(const float* __restrict__ W, _Float16* __restrict__ WT,
                int K, int N) {
    __shared__ float tile[32][33];
    const int tx = threadIdx.x;          // 0..31
    const int ty = threadIdx.y;          // 0..7
    const int n0 = blockIdx.x * 32;
    const int k0 = blockIdx.y * 32;
#pragma unroll
    for (int r = ty; r < 32; r += 8)
        tile[r][tx] = W[(size_t)(k0 + r) * N + n0 + tx];
    __syncthreads();
#pragma unroll
    for (int r = ty; r < 32; r += 8)
        WT[(size_t)(n0 + r) * K + k0 + tx] = (_Float16)tile[tx][r];
}

__global__ void copy_row(const float* __restrict__ W1, float* __restrict__ w1row, int N) {
    const int n = blockIdx.x * 256 + threadIdx.x;
    if (n < N) w1row[n] = W1[(size_t)1024 * N + n];
}

__global__ void init_h(const float* __restrict__ h0, float* __restrict__ hstate,
                       _Float16* __restrict__ x, int n) {
    const int i = blockIdx.x * 256 + threadIdx.x;
    if (i < n) {
        const float v = h0[i];
        hstate[i] = v;
        x[i] = (_Float16)v;
    }
}

// ---------------- launch ----------------
extern "C" void kernel_launch(void* const* d_in, const int* in_sizes, int n_in,
                              void* d_out, int out_size, void* d_ws, size_t ws_size,
                              hipStream_t stream) {
    const int B = 4096, H = 1024, H2 = 2048;

    const float* h0 = (const float*)d_in[0];
    const float* W1 = (const float*)d_in[1];  // (1025, 2048)
    const float* b1 = (const float*)d_in[2];  // (2048,)
    const float* W2 = (const float*)d_in[3];  // (2048, 2048)
    const float* b2 = (const float*)d_in[4];  // (2048,)
    const float* W3 = (const float*)d_in[5];  // (2048, 1024)
    const float* b3 = (const float*)d_in[6];  // (1024,)

    float* hstate = (float*)d_out;            // B*H fp32 state, final answer

    char* ws = (char*)d_ws;
    _Float16* x    = (_Float16*)ws; ws += (size_t)B * H  * 2;  // GEMM1 input
    _Float16* a1   = (_Float16*)ws; ws += (size_t)B * H2 * 2;  // layer-1 act
    _Float16* a2   = (_Float16*)ws; ws += (size_t)B * H2 * 2;  // layer-2 act
    float*    accb = (float*)ws;    ws += (size_t)B * H  * 4;  // RK4 k-accum
    _Float16* W1T  = (_Float16*)ws; ws += (size_t)H2 * H  * 2; // (2048,1024)
    _Float16* W2T  = (_Float16*)ws; ws += (size_t)H2 * H2 * 2; // (2048,2048)
    _Float16* W3T  = (_Float16*)ws; ws += (size_t)H  * H2 * 2; // (1024,2048)
    float*   w1row = (float*)ws;    ws += (size_t)H2 * 4;      // t-row of W1, fp32

    // weight conversion + transpose (runs every call; weights restored by harness)
    const dim3 tblk(32, 8);
    transposeW<<<dim3(H2 / 32, H  / 32), tblk, 0, stream>>>(W1, W1T, H,  H2);
    transposeW<<<dim3(H2 / 32, H2 / 32), tblk, 0, stream>>>(W2, W2T, H2, H2);
    transposeW<<<dim3(H  / 32, H2 / 32), tblk, 0, stream>>>(W3, W3T, H2, H);
    copy_row<<<dim3(H2 / 256), 256, 0, stream>>>(W1, w1row, H2);
    init_h<<<dim3((B * H + 255) / 256), 256, 0, stream>>>(h0, hstate, x, B * H);

    const float dt  = 0.1f;
    const float dt2 = 0.05f;
    const float dt6 = dt / 6.0f;

    const dim3 blk(256);
    const int g12 = (B / 128) * (H2 / 128);   // 512 blocks, 1-D, XCD-mapped
    const int g3  = (B / 64) * (H / 128);     // 512 blocks, 1-D, XCD-mapped

    for (int s = 0; s < 10; ++s) {
        const float ti = (float)s * dt;

        // k1 = f(ti, h)
        gemm_bias_tanh<true , 32, 16><<<g12, blk, 0, stream>>>(x,  W1T, a1, b1, w1row, ti,       H2, H);
        gemm_bias_tanh<false, 32, 16><<<g12, blk, 0, stream>>>(a1, W2T, a2, b2, nullptr, 0.f,    H2, H2);
        gemm_k_stage<<<g3, blk, 0, stream>>>(a2, W3T, b3, hstate, accb, x, 0, dt2, dt6, H, H2);

        // k2 = f(ti+dt/2, h + dt/2*k1)
        gemm_bias_tanh<true , 32, 16><<<g12, blk, 0, stream>>>(x,  W1T, a1, b1, w1row, ti + dt2, H2, H);
        gemm_bias_tanh<false, 32, 16><<<g12, blk, 0, stream>>>(a1, W2T, a2, b2, nullptr, 0.f,    H2, H2);
        gemm_k_stage<<<g3, blk, 0, stream>>>(a2, W3T, b3, hstate, accb, x, 1, dt2, dt6, H, H2);

        // k3 = f(ti+dt/2, h + dt/2*k2)
        gemm_bias_tanh<true , 32, 16><<<g12, blk, 0, stream>>>(x,  W1T, a1, b1, w1row, ti + dt2, H2, H);
        gemm_bias_tanh<false, 32, 16><<<g12, blk, 0, stream>>>(a1, W2T, a2, b2, nullptr, 0.f,    H2, H2);
        gemm_k_stage<<<g3, blk, 0, stream>>>(a2, W3T, b3, hstate, accb, x, 2, dt,  dt6, H, H2);

        // k4 = f(ti+dt, h + dt*k3); h += dt/6*(k1+2k2+2k3+k4)
        gemm_bias_tanh<true , 32, 16><<<g12, blk, 0, stream>>>(x,  W1T, a1, b1, w1row, ti + dt,  H2, H);
        gemm_bias_tanh<false, 32, 16><<<g12, blk, 0, stream>>>(a1, W2T, a2, b2, nullptr, 0.f,    H2, H2);
        gemm_k_stage<<<g3, blk, 0, stream>>>(a2, W3T, b3, hstate, accb, x, 3, dt,  dt6, H, H2);
    }
}

// Round 5
// 4655.123 us; speedup vs baseline: 1.4506x; 1.1286x over previous
//
#include <hip/hip_runtime.h>
#include <cstdint>
#include <cstddef>

// ---------------- types ----------------
typedef _Float16 half8 __attribute__((ext_vector_type(8)));
typedef float floatx4 __attribute__((ext_vector_type(4)));

typedef __attribute__((address_space(3))) unsigned lds_u32;
typedef const __attribute__((address_space(1))) unsigned glb_u32;

#define BK 64   // two 32-k sub-tiles per LDS buffer; halves barrier-drain count

__device__ __forceinline__ void glds16(const void* g, void* l) {
    // async global->LDS, 16B per lane; LDS dest = wave-uniform base + lane*16
    __builtin_amdgcn_global_load_lds((glb_u32*)g, (lds_u32*)l, 16, 0, 0);
}

__device__ __forceinline__ float fast_tanh(float x) {
    float ax = fabsf(x);
    float e  = __expf(-2.0f * ax);
    float t  = (1.0f - e) / (1.0f + e);
    return x < 0.0f ? -t : t;
}

// ---------------- XCD-aware block mapping ----------------
template <int MT, int NT, int NPX>
__device__ __forceinline__ void map_block(int id, int& mt, int& nt) {
    constexpr int NG  = NT / NPX;   // n-groups
    constexpr int XPG = 8 / NG;     // XCDs per group
    const int xcd  = id & 7;
    const int slot = id >> 3;
    nt = (xcd % NG) * NPX + (slot % NPX);
    mt = (xcd / NG) * (MT / XPG) + slot / NPX;
}

// ---------------- GEMM core, double-buffered, conflict-free swizzle --------
// C[TBM x TBN] = A[TBM x K] * BT[TBN x K]^T, both fp16 row-major (BT = B^T).
// Per 16-row x 32-k chunk (512 elems): staging lane j (row j>>2) fetches
// 16B k-chunk kq = (j&3) ^ ((j>>3)&3) of the row's 64B -> LDS unit j.
// Fragment read: lane (quad,l16) wants (row=l16, kq=quad) -> unit
// l16*4 + (quad ^ ((l16>>1)&3)). Every consecutive 8-lane window then covers
// all 8 bank-groups exactly once (round-4's (quad^(l16&3)) only permuted unit
// bits[1:0]; group MSB = l16 bit0 was unmixed -> 2-way, 4 cyc/read measured).
// Staging stays 64B-contiguous per 4-lane group (coalesced, round-2 property).
template <int TBM, int TBN, int MF, int NF>
__device__ __forceinline__ void gemm_acc_db(const _Float16* __restrict__ A,
                                            const _Float16* __restrict__ BT,
                                            size_t m0, size_t n0,
                                            int K, floatx4 acc[MF][NF]) {
    constexpr int CW = TBN / (16 * NF);   // waves along n
    static_assert((TBM / (16 * MF)) * CW == 4, "wave layout must use 4 waves");
    constexpr int AH = TBM * 32;          // elems per 32-k half of A tile
    constexpr int BH = TBN * 32;

    __shared__ __align__(16) _Float16 As[2][TBM * BK];
    __shared__ __align__(16) _Float16 Bs[2][TBN * BK];

    const int tid  = threadIdx.x;
    const int lane = tid & 63;
    const int wid  = tid >> 6;

    const int srow = lane >> 2;                     // row within 16-row chunk
    const int skq  = (lane & 3) ^ ((lane >> 3) & 3);// swizzled 16B k-chunk
    const int quad = lane >> 4;
    const int l16  = lane & 15;
    const int wm   = (wid / CW) * (16 * MF);
    const int wn   = (wid % CW) * (16 * NF);

#pragma unroll
    for (int i = 0; i < MF; ++i)
#pragma unroll
        for (int j = 0; j < NF; ++j)
            acc[i][j] = 0.0f;

    auto stage = [&](int buf, int k0) {
#pragma unroll
        for (int h = 0; h < 2; ++h) {
#pragma unroll
            for (int c = wid; c < TBM / 16; c += 4)
                glds16(A + (m0 + c * 16 + srow) * (size_t)K + k0 + h * 32 + skq * 8,
                       &As[buf][h * AH + c * 512]);
#pragma unroll
            for (int c = wid; c < TBN / 16; c += 4)
                glds16(BT + (n0 + c * 16 + srow) * (size_t)K + k0 + h * 32 + skq * 8,
                       &Bs[buf][h * BH + c * 512]);
        }
    };

    const int rdoff = l16 * 32 + ((quad ^ ((l16 >> 1) & 3)) << 3);

    stage(0, 0);
    int cur = 0;
    for (int k0 = 0; k0 < K; k0 += BK) {
        __syncthreads();                           // buf[cur] ready (vmcnt drain)
        if (k0 + BK < K) stage(cur ^ 1, k0 + BK);  // overlap with MFMAs below

#pragma unroll
        for (int h = 0; h < 2; ++h) {
            half8 av[MF], bv[NF];
#pragma unroll
            for (int i = 0; i < MF; ++i)
                av[i] = *(const half8*)(&As[cur][h * AH + ((wm >> 4) + i) * 512 + rdoff]);
#pragma unroll
            for (int j = 0; j < NF; ++j)
                bv[j] = *(const half8*)(&Bs[cur][h * BH + ((wn >> 4) + j) * 512 + rdoff]);
#pragma unroll
            for (int i = 0; i < MF; ++i)
#pragma unroll
                for (int j = 0; j < NF; ++j)
                    acc[i][j] = __builtin_amdgcn_mfma_f32_16x16x32_f16(av[i], bv[j], acc[i][j], 0, 0, 0);
        }
        cur ^= 1;
    }
}

// C/D layout (verified m89/m91): col = lane&15, row = quad*4 + reg.

// ---------------- GEMM + bias (+ t*brow) + tanh -> fp16 out ----------------
template <bool WITH_T, int MT, int NT>
__global__ __launch_bounds__(256)
void gemm_bias_tanh(const _Float16* __restrict__ A, const _Float16* __restrict__ BT,
                    _Float16* __restrict__ out, const float* __restrict__ bias,
                    const float* __restrict__ brow, float t, int N, int K) {
    int mt, nt;
    map_block<MT, NT, 4>(blockIdx.x, mt, nt);
    const size_t bm0 = (size_t)mt * 128;
    const size_t bn0 = (size_t)nt * 128;

    floatx4 acc[4][4];
    gemm_acc_db<128, 128, 4, 4>(A, BT, bm0, bn0, K, acc);

    const int tid  = threadIdx.x;
    const int lane = tid & 63;
    const int wid  = tid >> 6;
    const int quad = lane >> 4;
    const int l16  = lane & 15;
    const size_t m0 = bm0 + (size_t)(wid / 2) * 64;
    const size_t n0 = bn0 + (size_t)(wid % 2) * 64;

#pragma unroll
    for (int j = 0; j < 4; ++j) {
        const size_t col = n0 + j * 16 + l16;
        float b = bias[col];
        if (WITH_T) b += t * brow[col];
#pragma unroll
        for (int i = 0; i < 4; ++i) {
            const size_t rbase = m0 + i * 16 + quad * 4;
#pragma unroll
            for (int r = 0; r < 4; ++r) {
                out[(rbase + r) * (size_t)N + col] = (_Float16)fast_tanh(acc[i][j][r] + b);
            }
        }
    }
}

// ---------------- GEMM3 (64x128 tile) + fused RK4 stage update ----------------
__global__ __launch_bounds__(256)
void gemm_k_stage(const _Float16* __restrict__ A, const _Float16* __restrict__ BT,
                  const float* __restrict__ bias, float* __restrict__ hstate,
                  float* __restrict__ accb, _Float16* __restrict__ x,
                  int stage, float c, float dt6, int N, int K) {
    int mt, nt;
    map_block<64, 8, 2>(blockIdx.x, mt, nt);
    const size_t bm0 = (size_t)mt * 64;
    const size_t bn0 = (size_t)nt * 128;

    floatx4 acc[4][2];
    gemm_acc_db<64, 128, 4, 2>(A, BT, bm0, bn0, K, acc);

    const int tid  = threadIdx.x;
    const int lane = tid & 63;
    const int wid  = tid >> 6;
    const int quad = lane >> 4;
    const int l16  = lane & 15;
    // wave layout for <64,128,4,2>: CW=4 -> wm = 0, wn = wid*32
    const size_t m0 = bm0;
    const size_t n0 = bn0 + (size_t)wid * 32;

#pragma unroll
    for (int j = 0; j < 2; ++j) {
        const size_t col = n0 + j * 16 + l16;
        const float b = bias[col];
#pragma unroll
        for (int i = 0; i < 4; ++i) {
            const size_t rbase = m0 + i * 16 + quad * 4;
#pragma unroll
            for (int r = 0; r < 4; ++r) {
                const size_t idx = (rbase + r) * (size_t)N + col;
                const float k = acc[i][j][r] + b;
                if (stage == 0) {
                    accb[idx] = k;
                    x[idx] = (_Float16)(hstate[idx] + c * k);
                } else if (stage < 3) {
                    accb[idx] += 2.0f * k;
                    x[idx] = (_Float16)(hstate[idx] + c * k);
                } else {
                    const float hn = hstate[idx] + dt6 * (accb[idx] + k);
                    hstate[idx] = hn;
                    x[idx] = (_Float16)hn;
                }
            }
        }
    }
}

// ---------------- setup kernels ----------------
__global__ __launch_bounds__(256)
void transposeW(const float* __restrict__ W, _Float16* __restrict__ WT,
                int K, int N) {
    __shared__ float tile[32][33];
    const int tx = threadIdx.x;          // 0..31
    const int ty = threadIdx.y;          // 0..7
    const int n0 = blockIdx.x * 32;
    const int k0 = blockIdx.y * 32;
#pragma unroll
    for (int r = ty; r < 32; r += 8)
        tile[r][tx] = W[(size_t)(k0 + r) * N + n0 + tx];
    __syncthreads();
#pragma unroll
    for (int r = ty; r < 32; r += 8)
        WT[(size_t)(n0 + r) * K + k0 + tx] = (_Float16)tile[tx][r];
}

__global__ void copy_row(const float* __restrict__ W1, float* __restrict__ w1row, int N) {
    const int n = blockIdx.x * 256 + threadIdx.x;
    if (n < N) w1row[n] = W1[(size_t)1024 * N + n];
}

__global__ void init_h(const float* __restrict__ h0, float* __restrict__ hstate,
                       _Float16* __restrict__ x, int n) {
    const int i = blockIdx.x * 256 + threadIdx.x;
    if (i < n) {
        const float v = h0[i];
        hstate[i] = v;
        x[i] = (_Float16)v;
    }
}

// ---------------- launch ----------------
extern "C" void kernel_launch(void* const* d_in, const int* in_sizes, int n_in,
                              void* d_out, int out_size, void* d_ws, size_t ws_size,
                              hipStream_t stream) {
    const int B = 4096, H = 1024, H2 = 2048;

    const float* h0 = (const float*)d_in[0];
    const float* W1 = (const float*)d_in[1];  // (1025, 2048)
    const float* b1 = (const float*)d_in[2];  // (2048,)
    const float* W2 = (const float*)d_in[3];  // (2048, 2048)
    const float* b2 = (const float*)d_in[4];  // (2048,)
    const float* W3 = (const float*)d_in[5];  // (2048, 1024)
    const float* b3 = (const float*)d_in[6];  // (1024,)

    float* hstate = (float*)d_out;            // B*H fp32 state, final answer

    char* ws = (char*)d_ws;
    _Float16* x    = (_Float16*)ws; ws += (size_t)B * H  * 2;  // GEMM1 input
    _Float16* a1   = (_Float16*)ws; ws += (size_t)B * H2 * 2;  // layer-1 act
    _Float16* a2   = (_Float16*)ws; ws += (size_t)B * H2 * 2;  // layer-2 act
    float*    accb = (float*)ws;    ws += (size_t)B * H  * 4;  // RK4 k-accum
    _Float16* W1T  = (_Float16*)ws; ws += (size_t)H2 * H  * 2; // (2048,1024)
    _Float16* W2T  = (_Float16*)ws; ws += (size_t)H2 * H2 * 2; // (2048,2048)
    _Float16* W3T  = (_Float16*)ws; ws += (size_t)H  * H2 * 2; // (1024,2048)
    float*   w1row = (float*)ws;    ws += (size_t)H2 * 4;      // t-row of W1, fp32

    // weight conversion + transpose (runs every call; weights restored by harness)
    const dim3 tblk(32, 8);
    transposeW<<<dim3(H2 / 32, H  / 32), tblk, 0, stream>>>(W1, W1T, H,  H2);
    transposeW<<<dim3(H2 / 32, H2 / 32), tblk, 0, stream>>>(W2, W2T, H2, H2);
    transposeW<<<dim3(H  / 32, H2 / 32), tblk, 0, stream>>>(W3, W3T, H2, H);
    copy_row<<<dim3(H2 / 256), 256, 0, stream>>>(W1, w1row, H2);
    init_h<<<dim3((B * H + 255) / 256), 256, 0, stream>>>(h0, hstate, x, B * H);

    const float dt  = 0.1f;
    const float dt2 = 0.05f;
    const float dt6 = dt / 6.0f;

    const dim3 blk(256);
    const int g12 = (B / 128) * (H2 / 128);   // 512 blocks, 1-D, XCD-mapped
    const int g3  = (B / 64) * (H / 128);     // 512 blocks, 1-D, XCD-mapped

    for (int s = 0; s < 10; ++s) {
        const float ti = (float)s * dt;

        // k1 = f(ti, h)
        gemm_bias_tanh<true , 32, 16><<<g12, blk, 0, stream>>>(x,  W1T, a1, b1, w1row, ti,       H2, H);
        gemm_bias_tanh<false, 32, 16><<<g12, blk, 0, stream>>>(a1, W2T, a2, b2, nullptr, 0.f,    H2, H2);
        gemm_k_stage<<<g3, blk, 0, stream>>>(a2, W3T, b3, hstate, accb, x, 0, dt2, dt6, H, H2);

        // k2 = f(ti+dt/2, h + dt/2*k1)
        gemm_bias_tanh<true , 32, 16><<<g12, blk, 0, stream>>>(x,  W1T, a1, b1, w1row, ti + dt2, H2, H);
        gemm_bias_tanh<false, 32, 16><<<g12, blk, 0, stream>>>(a1, W2T, a2, b2, nullptr, 0.f,    H2, H2);
        gemm_k_stage<<<g3, blk, 0, stream>>>(a2, W3T, b3, hstate, accb, x, 1, dt2, dt6, H, H2);

        // k3 = f(ti+dt/2, h + dt/2*k2)
        gemm_bias_tanh<true , 32, 16><<<g12, blk, 0, stream>>>(x,  W1T, a1, b1, w1row, ti + dt2, H2, H);
        gemm_bias_tanh<false, 32, 16><<<g12, blk, 0, stream>>>(a1, W2T, a2, b2, nullptr, 0.f,    H2, H2);
        gemm_k_stage<<<g3, blk, 0, stream>>>(a2, W3T, b3, hstate, accb, x, 2, dt,  dt6, H, H2);

        // k4 = f(ti+dt, h + dt*k3); h += dt/6*(k1+2k2+2k3+k4)
        gemm_bias_tanh<true , 32, 16><<<g12, blk, 0, stream>>>(x,  W1T, a1, b1, w1row, ti + dt,  H2, H);
        gemm_bias_tanh<false, 32, 16><<<g12, blk, 0, stream>>>(a1, W2T, a2, b2, nullptr, 0.f,    H2, H2);
        gemm_k_stage<<<g3, blk, 0, stream>>>(a2, W3T, b3, hstate, accb, x, 3, dt,  dt6, H, H2);
    }
}

// Round 6
// 4325.357 us; speedup vs baseline: 1.5612x; 1.0762x over previous
//
#include <hip/hip_runtime.h>
#include <cstdint>
#include <cstddef>

// ---------------- types ----------------
typedef _Float16 half8 __attribute__((ext_vector_type(8)));
typedef float floatx4 __attribute__((ext_vector_type(4)));

typedef __attribute__((address_space(3))) unsigned lds_u32;
typedef const __attribute__((address_space(1))) unsigned glb_u32;

#define BK 64   // two 32-k sub-tiles per LDS buffer; halves barrier-drain count

__device__ __forceinline__ void glds16(const void* g, void* l) {
    // async global->LDS, 16B per lane; LDS dest = wave-uniform base + lane*16
    __builtin_amdgcn_global_load_lds((glb_u32*)g, (lds_u32*)l, 16, 0, 0);
}

__device__ __forceinline__ float fast_tanh(float x) {
    float ax = fabsf(x);
    float e  = __expf(-2.0f * ax);
    float t  = (1.0f - e) / (1.0f + e);
    return x < 0.0f ? -t : t;
}

// ---------------- XCD-aware block mapping ----------------
template <int MT, int NT, int NPX>
__device__ __forceinline__ void map_block(int id, int& mt, int& nt) {
    constexpr int NG  = NT / NPX;   // n-groups
    constexpr int XPG = 8 / NG;     // XCDs per group
    const int xcd  = id & 7;
    const int slot = id >> 3;
    nt = (xcd % NG) * NPX + (slot % NPX);
    mt = (xcd / NG) * (MT / XPG) + slot / NPX;
}

// ---------------- GEMM core, double-buffered, conflict-free swizzle --------
// C[TBM x TBN] = A[TBM x K] * BT[TBN x K]^T, both fp16 row-major (BT = B^T).
// NW waves, wave grid RW x CW, wave tile (16*MF) x (16*NF).
// Per 16-row x 32-k chunk (512 elems): staging lane j (row j>>2) fetches
// 16B k-chunk kq = (j&3) ^ ((j>>3)&3) of the row's 64B -> LDS unit j.
// Fragment read: lane (quad,l16) wants (row=l16, kq=quad) -> unit
// l16*4 + (quad ^ ((l16>>1)&3)): every 8-lane window covers all 8 bank-groups
// once (verified round 5: conflicts 4.19M -> 0). Staging stays 64B-contiguous
// per 4-lane group (coalesced).
// Round 6: NW=8 (512-thr blocks) -> 16 waves/CU at 2 blocks/CU, hiding the
// per-iter vmcnt(0) barrier drain with TLP (2 waves/SIMD was not enough).
template <int TBM, int TBN, int MF, int NF, int NW>
__device__ __forceinline__ void gemm_acc_db(const _Float16* __restrict__ A,
                                            const _Float16* __restrict__ BT,
                                            size_t m0, size_t n0,
                                            int K, floatx4 acc[MF][NF]) {
    constexpr int CW = TBN / (16 * NF);   // waves along n
    constexpr int RW = TBM / (16 * MF);   // waves along m
    static_assert(RW * CW == NW, "wave grid must use all waves");
    constexpr int AH = TBM * 32;          // elems per 32-k half of A tile
    constexpr int BH = TBN * 32;

    __shared__ __align__(16) _Float16 As[2][TBM * BK];
    __shared__ __align__(16) _Float16 Bs[2][TBN * BK];

    const int tid  = threadIdx.x;
    const int lane = tid & 63;
    const int wid  = tid >> 6;

    const int srow = lane >> 2;                     // row within 16-row chunk
    const int skq  = (lane & 3) ^ ((lane >> 3) & 3);// swizzled 16B k-chunk
    const int quad = lane >> 4;
    const int l16  = lane & 15;
    const int wm   = (wid / CW) * (16 * MF);
    const int wn   = (wid % CW) * (16 * NF);

#pragma unroll
    for (int i = 0; i < MF; ++i)
#pragma unroll
        for (int j = 0; j < NF; ++j)
            acc[i][j] = 0.0f;

    auto stage = [&](int buf, int k0) {
#pragma unroll
        for (int h = 0; h < 2; ++h) {
#pragma unroll
            for (int c = wid; c < TBM / 16; c += NW)
                glds16(A + (m0 + c * 16 + srow) * (size_t)K + k0 + h * 32 + skq * 8,
                       &As[buf][h * AH + c * 512]);
#pragma unroll
            for (int c = wid; c < TBN / 16; c += NW)
                glds16(BT + (n0 + c * 16 + srow) * (size_t)K + k0 + h * 32 + skq * 8,
                       &Bs[buf][h * BH + c * 512]);
        }
    };

    const int rdoff = l16 * 32 + ((quad ^ ((l16 >> 1) & 3)) << 3);

    stage(0, 0);
    int cur = 0;
    for (int k0 = 0; k0 < K; k0 += BK) {
        __syncthreads();                           // buf[cur] ready (vmcnt drain)
        if (k0 + BK < K) stage(cur ^ 1, k0 + BK);  // overlap with MFMAs below

#pragma unroll
        for (int h = 0; h < 2; ++h) {
            half8 av[MF], bv[NF];
#pragma unroll
            for (int i = 0; i < MF; ++i)
                av[i] = *(const half8*)(&As[cur][h * AH + ((wm >> 4) + i) * 512 + rdoff]);
#pragma unroll
            for (int j = 0; j < NF; ++j)
                bv[j] = *(const half8*)(&Bs[cur][h * BH + ((wn >> 4) + j) * 512 + rdoff]);
#pragma unroll
            for (int i = 0; i < MF; ++i)
#pragma unroll
                for (int j = 0; j < NF; ++j)
                    acc[i][j] = __builtin_amdgcn_mfma_f32_16x16x32_f16(av[i], bv[j], acc[i][j], 0, 0, 0);
        }
        cur ^= 1;
    }
}

// C/D layout (verified m89/m91): col = lane&15, row = quad*4 + reg.

// ---------------- GEMM + bias (+ t*brow) + tanh -> fp16 out ----------------
// 128x128 tile, 512 threads (8 waves of 64x32), 1-D grid, XCD-mapped.
template <bool WITH_T, int MT, int NT>
__global__ __launch_bounds__(512)
void gemm_bias_tanh(const _Float16* __restrict__ A, const _Float16* __restrict__ BT,
                    _Float16* __restrict__ out, const float* __restrict__ bias,
                    const float* __restrict__ brow, float t, int N, int K) {
    int mt, nt;
    map_block<MT, NT, 4>(blockIdx.x, mt, nt);
    const size_t bm0 = (size_t)mt * 128;
    const size_t bn0 = (size_t)nt * 128;

    floatx4 acc[4][2];
    gemm_acc_db<128, 128, 4, 2, 8>(A, BT, bm0, bn0, K, acc);

    const int tid  = threadIdx.x;
    const int lane = tid & 63;
    const int wid  = tid >> 6;          // 0..7; wave grid 2 (m) x 4 (n)
    const int quad = lane >> 4;
    const int l16  = lane & 15;
    const size_t m0 = bm0 + (size_t)(wid / 4) * 64;
    const size_t n0 = bn0 + (size_t)(wid % 4) * 32;

#pragma unroll
    for (int j = 0; j < 2; ++j) {
        const size_t col = n0 + j * 16 + l16;
        float b = bias[col];
        if (WITH_T) b += t * brow[col];
#pragma unroll
        for (int i = 0; i < 4; ++i) {
            const size_t rbase = m0 + i * 16 + quad * 4;
#pragma unroll
            for (int r = 0; r < 4; ++r) {
                out[(rbase + r) * (size_t)N + col] = (_Float16)fast_tanh(acc[i][j][r] + b);
            }
        }
    }
}

// ---------------- GEMM3 (64x128 tile, 8 waves of 32x32) + RK4 stage --------
__global__ __launch_bounds__(512)
void gemm_k_stage(const _Float16* __restrict__ A, const _Float16* __restrict__ BT,
                  const float* __restrict__ bias, float* __restrict__ hstate,
                  float* __restrict__ accb, _Float16* __restrict__ x,
                  int stage, float c, float dt6, int N, int K) {
    int mt, nt;
    map_block<64, 8, 2>(blockIdx.x, mt, nt);
    const size_t bm0 = (size_t)mt * 64;
    const size_t bn0 = (size_t)nt * 128;

    floatx4 acc[2][2];
    gemm_acc_db<64, 128, 2, 2, 8>(A, BT, bm0, bn0, K, acc);

    const int tid  = threadIdx.x;
    const int lane = tid & 63;
    const int wid  = tid >> 6;          // wave grid 2 (m) x 4 (n)
    const int quad = lane >> 4;
    const int l16  = lane & 15;
    const size_t m0 = bm0 + (size_t)(wid / 4) * 32;
    const size_t n0 = bn0 + (size_t)(wid % 4) * 32;

#pragma unroll
    for (int j = 0; j < 2; ++j) {
        const size_t col = n0 + j * 16 + l16;
        const float b = bias[col];
#pragma unroll
        for (int i = 0; i < 2; ++i) {
            const size_t rbase = m0 + i * 16 + quad * 4;
#pragma unroll
            for (int r = 0; r < 4; ++r) {
                const size_t idx = (rbase + r) * (size_t)N + col;
                const float k = acc[i][j][r] + b;
                if (stage == 0) {
                    accb[idx] = k;
                    x[idx] = (_Float16)(hstate[idx] + c * k);
                } else if (stage < 3) {
                    accb[idx] += 2.0f * k;
                    x[idx] = (_Float16)(hstate[idx] + c * k);
                } else {
                    const float hn = hstate[idx] + dt6 * (accb[idx] + k);
                    hstate[idx] = hn;
                    x[idx] = (_Float16)hn;
                }
            }
        }
    }
}

// ---------------- setup kernels ----------------
__global__ __launch_bounds__(256)
void transposeW(const float* __restrict__ W, _Float16* __restrict__ WT,
                int K, int N) {
    __shared__ float tile[32][33];
    const int tx = threadIdx.x;          // 0..31
    const int ty = threadIdx.y;          // 0..7
    const int n0 = blockIdx.x * 32;
    const int k0 = blockIdx.y * 32;
#pragma unroll
    for (int r = ty; r < 32; r += 8)
        tile[r][tx] = W[(size_t)(k0 + r) * N + n0 + tx];
    __syncthreads();
#pragma unroll
    for (int r = ty; r < 32; r += 8)
        WT[(size_t)(n0 + r) * K + k0 + tx] = (_Float16)tile[tx][r];
}

__global__ void copy_row(const float* __restrict__ W1, float* __restrict__ w1row, int N) {
    const int n = blockIdx.x * 256 + threadIdx.x;
    if (n < N) w1row[n] = W1[(size_t)1024 * N + n];
}

__global__ void init_h(const float* __restrict__ h0, float* __restrict__ hstate,
                       _Float16* __restrict__ x, int n) {
    const int i = blockIdx.x * 256 + threadIdx.x;
    if (i < n) {
        const float v = h0[i];
        hstate[i] = v;
        x[i] = (_Float16)v;
    }
}

// ---------------- launch ----------------
extern "C" void kernel_launch(void* const* d_in, const int* in_sizes, int n_in,
                              void* d_out, int out_size, void* d_ws, size_t ws_size,
                              hipStream_t stream) {
    const int B = 4096, H = 1024, H2 = 2048;

    const float* h0 = (const float*)d_in[0];
    const float* W1 = (const float*)d_in[1];  // (1025, 2048)
    const float* b1 = (const float*)d_in[2];  // (2048,)
    const float* W2 = (const float*)d_in[3];  // (2048, 2048)
    const float* b2 = (const float*)d_in[4];  // (2048,)
    const float* W3 = (const float*)d_in[5];  // (2048, 1024)
    const float* b3 = (const float*)d_in[6];  // (1024,)

    float* hstate = (float*)d_out;            // B*H fp32 state, final answer

    char* ws = (char*)d_ws;
    _Float16* x    = (_Float16*)ws; ws += (size_t)B * H  * 2;  // GEMM1 input
    _Float16* a1   = (_Float16*)ws; ws += (size_t)B * H2 * 2;  // layer-1 act
    _Float16* a2   = (_Float16*)ws; ws += (size_t)B * H2 * 2;  // layer-2 act
    float*    accb = (float*)ws;    ws += (size_t)B * H  * 4;  // RK4 k-accum
    _Float16* W1T  = (_Float16*)ws; ws += (size_t)H2 * H  * 2; // (2048,1024)
    _Float16* W2T  = (_Float16*)ws; ws += (size_t)H2 * H2 * 2; // (2048,2048)
    _Float16* W3T  = (_Float16*)ws; ws += (size_t)H  * H2 * 2; // (1024,2048)
    float*   w1row = (float*)ws;    ws += (size_t)H2 * 4;      // t-row of W1, fp32

    // weight conversion + transpose (runs every call; weights restored by harness)
    const dim3 tblk(32, 8);
    transposeW<<<dim3(H2 / 32, H  / 32), tblk, 0, stream>>>(W1, W1T, H,  H2);
    transposeW<<<dim3(H2 / 32, H2 / 32), tblk, 0, stream>>>(W2, W2T, H2, H2);
    transposeW<<<dim3(H  / 32, H2 / 32), tblk, 0, stream>>>(W3, W3T, H2, H);
    copy_row<<<dim3(H2 / 256), 256, 0, stream>>>(W1, w1row, H2);
    init_h<<<dim3((B * H + 255) / 256), 256, 0, stream>>>(h0, hstate, x, B * H);

    const float dt  = 0.1f;
    const float dt2 = 0.05f;
    const float dt6 = dt / 6.0f;

    const dim3 blk(512);
    const int g12 = (B / 128) * (H2 / 128);   // 512 blocks, 1-D, XCD-mapped
    const int g3  = (B / 64) * (H / 128);     // 512 blocks, 1-D, XCD-mapped

    for (int s = 0; s < 10; ++s) {
        const float ti = (float)s * dt;

        // k1 = f(ti, h)
        gemm_bias_tanh<true , 32, 16><<<g12, blk, 0, stream>>>(x,  W1T, a1, b1, w1row, ti,       H2, H);
        gemm_bias_tanh<false, 32, 16><<<g12, blk, 0, stream>>>(a1, W2T, a2, b2, nullptr, 0.f,    H2, H2);
        gemm_k_stage<<<g3, blk, 0, stream>>>(a2, W3T, b3, hstate, accb, x, 0, dt2, dt6, H, H2);

        // k2 = f(ti+dt/2, h + dt/2*k1)
        gemm_bias_tanh<true , 32, 16><<<g12, blk, 0, stream>>>(x,  W1T, a1, b1, w1row, ti + dt2, H2, H);
        gemm_bias_tanh<false, 32, 16><<<g12, blk, 0, stream>>>(a1, W2T, a2, b2, nullptr, 0.f,    H2, H2);
        gemm_k_stage<<<g3, blk, 0, stream>>>(a2, W3T, b3, hstate, accb, x, 1, dt2, dt6, H, H2);

        // k3 = f(ti+dt/2, h + dt/2*k2)
        gemm_bias_tanh<true , 32, 16><<<g12, blk, 0, stream>>>(x,  W1T, a1, b1, w1row, ti + dt2, H2, H);
        gemm_bias_tanh<false, 32, 16><<<g12, blk, 0, stream>>>(a1, W2T, a2, b2, nullptr, 0.f,    H2, H2);
        gemm_k_stage<<<g3, blk, 0, stream>>>(a2, W3T, b3, hstate, accb, x, 2, dt,  dt6, H, H2);

        // k4 = f(ti+dt, h + dt*k3); h += dt/6*(k1+2k2+2k3+k4)
        gemm_bias_tanh<true , 32, 16><<<g12, blk, 0, stream>>>(x,  W1T, a1, b1, w1row, ti + dt,  H2, H);
        gemm_bias_tanh<false, 32, 16><<<g12, blk, 0, stream>>>(a1, W2T, a2, b2, nullptr, 0.f,    H2, H2);
        gemm_k_stage<<<g3, blk, 0, stream>>>(a2, W3T, b3, hstate, accb, x, 3, dt,  dt6, H, H2);
    }
}